// Round 2
// baseline (699.681 us; speedup 1.0000x reference)
//
#include <hip/hip_runtime.h>
#include <stdint.h>

typedef unsigned short u16;
typedef short bf16x8 __attribute__((ext_vector_type(8)));
typedef float f32x4 __attribute__((ext_vector_type(4)));
typedef u16 u16x4 __attribute__((ext_vector_type(4)));
typedef u16 u16x8 __attribute__((ext_vector_type(8)));

#define LOG2E 1.4426950408889634f

__device__ __forceinline__ u16 f2bf(float f) {
  union { float f; uint32_t u; } x; x.f = f;
  uint32_t r = x.u + 0x7fffu + ((x.u >> 16) & 1u);
  return (u16)(r >> 16);
}
__device__ __forceinline__ float bf2f(u16 h) {
  union { uint32_t u; float f; } x; x.u = ((uint32_t)h) << 16;
  return x.f;
}

__device__ __forceinline__ void gload_lds16(const void* g, void* lds) {
  __builtin_amdgcn_global_load_lds(
      (const __attribute__((address_space(1))) void*)g,
      (__attribute__((address_space(3))) void*)lds, 16, 0, 0);
}

// ---------------- cast f32 -> bf16 (8 elems/thread) ----------------
__global__ __launch_bounds__(256) void cast_bf16(const float* __restrict__ in,
                                                 u16* __restrict__ out, int n8) {
  int i = blockIdx.x * 256 + threadIdx.x;
  const int stride = gridDim.x * 256;
  for (; i < n8; i += stride) {
    const f32x4* p = (const f32x4*)in + (size_t)i * 2;
    f32x4 a = p[0], b = p[1];
    u16x8 o;
    o[0] = f2bf(a[0]); o[1] = f2bf(a[1]); o[2] = f2bf(a[2]); o[3] = f2bf(a[3]);
    o[4] = f2bf(b[0]); o[5] = f2bf(b[1]); o[6] = f2bf(b[2]); o[7] = f2bf(b[3]);
    ((u16x8*)out)[i] = o;
  }
}

// ---------------- transpose + cast: W[R][C] f32 -> WT[C][R] bf16 ----------------
__global__ __launch_bounds__(256) void transpose_cast(const float* __restrict__ in,
                                                      u16* __restrict__ out, int R, int C) {
  __shared__ float tile[32][33];
  const int bc = blockIdx.x * 32, br = blockIdx.y * 32;
  const int tx = threadIdx.x & 31, ty = threadIdx.x >> 5;  // 32 x 8
#pragma unroll
  for (int i = 0; i < 32; i += 8)
    tile[ty + i][tx] = in[(size_t)(br + ty + i) * C + bc + tx];
  __syncthreads();
#pragma unroll
  for (int i = 0; i < 32; i += 8)
    out[(size_t)(bc + ty + i) * R + br + tx] = f2bf(tile[tx][ty + i]);
}

// ---------------- GEMM: C[M][N] = A[M][K] @ BT[N][K]^T + bias ----------------
// m97 structure: 128x128 tile, BK=64, 4 waves (2x2), global_load_lds width-16.
template <int RELU>
__global__ __launch_bounds__(256) void gemm_bt(const u16* __restrict__ A,
                                               const u16* __restrict__ BT,
                                               const float* __restrict__ bias,
                                               u16* __restrict__ Cb,
                                               int M, int N, int K) {
  constexpr int BM = 128, BN = 128, BK = 64;
  __shared__ u16 As[BM * BK];
  __shared__ u16 Bs[BN * BK];
  const int t = threadIdx.x;
  const int w = t >> 6, lane = t & 63;
  const int la = lane & 15, lb = lane >> 4;
  const int wr = w >> 1, wc = w & 1;
  const int m0 = blockIdx.y * BM, n0 = blockIdx.x * BN;

  f32x4 acc[4][4];
#pragma unroll
  for (int i = 0; i < 4; i++)
#pragma unroll
    for (int j = 0; j < 4; j++) acc[i][j] = (f32x4){0.f, 0.f, 0.f, 0.f};

  for (int kt = 0; kt < K; kt += BK) {
#pragma unroll
    for (int i = 0; i < 4; i++) {
      const int s = i * 256 + t;
      const int row = s >> 3, col = (s & 7) * 8;
      gload_lds16(A + (size_t)(m0 + row) * K + kt + col, &As[(i * 256 + w * 64) * 8]);
      gload_lds16(BT + (size_t)(n0 + row) * K + kt + col, &Bs[(i * 256 + w * 64) * 8]);
    }
    __syncthreads();
#pragma unroll
    for (int ks = 0; ks < 2; ks++) {
      bf16x8 af[4], bfr[4];
#pragma unroll
      for (int i = 0; i < 4; i++)
        af[i] = *(const bf16x8*)&As[(wr * 64 + i * 16 + la) * BK + ks * 32 + lb * 8];
#pragma unroll
      for (int j = 0; j < 4; j++)
        bfr[j] = *(const bf16x8*)&Bs[(wc * 64 + j * 16 + la) * BK + ks * 32 + lb * 8];
#pragma unroll
      for (int i = 0; i < 4; i++)
#pragma unroll
        for (int j = 0; j < 4; j++)
          acc[i][j] = __builtin_amdgcn_mfma_f32_16x16x32_bf16(af[i], bfr[j], acc[i][j], 0, 0, 0);
    }
    __syncthreads();
  }
#pragma unroll
  for (int i = 0; i < 4; i++) {
    const int r = m0 + wr * 64 + i * 16 + lb * 4;
#pragma unroll
    for (int j = 0; j < 4; j++) {
      const int c = n0 + wc * 64 + j * 16 + la;
      const float bv = bias[c];
#pragma unroll
      for (int rr = 0; rr < 4; rr++) {
        float v = acc[i][j][rr] + bv;
        if (RELU) v = fmaxf(v, 0.f);
        Cb[(size_t)(r + rr) * N + c] = f2bf(v);
      }
    }
  }
}

// ---------------- flash attention fwd ----------------
// grid: (S/128, H, B); 4 waves, each owns 32 q-rows. KVBLK=64.
__global__ __launch_bounds__(256) void attn_fwd(const u16* __restrict__ Qg,
                                                const u16* __restrict__ Kg,
                                                const u16* __restrict__ Vg,
                                                u16* __restrict__ Og) {
  constexpr int S = 2048, DM = 1024, DH = 64, QB = 128, KB = 64;
  __shared__ u16 Ks[KB * DH];  // [kv][dh]
  __shared__ u16 Vt[DH * KB];  // [dh][kv]
  __shared__ u16 Ps[QB * KB];  // [m][kv] (per-wave 32-row slices)
  const int t = threadIdx.x, w = t >> 6, lane = t & 63;
  const int la = lane & 15, lb = lane >> 4;
  const int qb = blockIdx.x, h = blockIdx.y, b = blockIdx.z;
  const size_t base = ((size_t)b * S) * DM + h * DH;
  const int qrow0 = qb * QB + w * 32;

  bf16x8 qf[2][2];
#pragma unroll
  for (int rf = 0; rf < 2; rf++)
#pragma unroll
    for (int ks = 0; ks < 2; ks++)
      qf[rf][ks] = *(const bf16x8*)&Qg[base + (size_t)(qrow0 + rf * 16 + la) * DM + ks * 32 + lb * 8];

  f32x4 accO[2][4];
  float mrow[2][4], lsum[2][4];
#pragma unroll
  for (int i = 0; i < 2; i++)
#pragma unroll
    for (int j = 0; j < 4; j++) accO[i][j] = (f32x4){0.f, 0.f, 0.f, 0.f};
#pragma unroll
  for (int i = 0; i < 2; i++)
#pragma unroll
    for (int rr = 0; rr < 4; rr++) { mrow[i][rr] = -1e30f; lsum[i][rr] = 0.f; }

  const float SC = 0.125f * LOG2E;

  for (int kt = 0; kt < S; kt += KB) {
    __syncthreads();
#pragma unroll
    for (int i = 0; i < 2; i++) {
      const int s = i * 256 + t;
      const int row = s >> 3, col = (s & 7) * 8;
      gload_lds16(Kg + base + (size_t)(kt + row) * DM + col, &Ks[(i * 256 + w * 64) * 8]);
    }
#pragma unroll
    for (int i = 0; i < 2; i++) {
      const int s = i * 256 + t;
      const int row = s >> 3, col = (s & 7) * 8;
      bf16x8 vv = *(const bf16x8*)&Vg[base + (size_t)(kt + row) * DM + col];
#pragma unroll
      for (int e = 0; e < 8; e++) Vt[(col + e) * KB + row] = (u16)vv[e];
    }
    __syncthreads();

    f32x4 sa[2][4];
#pragma unroll
    for (int i = 0; i < 2; i++)
#pragma unroll
      for (int j = 0; j < 4; j++) sa[i][j] = (f32x4){0.f, 0.f, 0.f, 0.f};
#pragma unroll
    for (int ks = 0; ks < 2; ks++) {
      bf16x8 kf[4];
#pragma unroll
      for (int j = 0; j < 4; j++)
        kf[j] = *(const bf16x8*)&Ks[(j * 16 + la) * DH + ks * 32 + lb * 8];
#pragma unroll
      for (int rf = 0; rf < 2; rf++)
#pragma unroll
        for (int j = 0; j < 4; j++)
          sa[rf][j] = __builtin_amdgcn_mfma_f32_16x16x32_bf16(qf[rf][ks], kf[j], sa[rf][j], 0, 0, 0);
    }

#pragma unroll
    for (int rf = 0; rf < 2; rf++) {
      float rmax[4], rsum[4];
#pragma unroll
      for (int rr = 0; rr < 4; rr++)
        rmax[rr] = fmaxf(fmaxf(sa[rf][0][rr], sa[rf][1][rr]), fmaxf(sa[rf][2][rr], sa[rf][3][rr]));
#pragma unroll
      for (int off = 1; off < 16; off <<= 1)
#pragma unroll
        for (int rr = 0; rr < 4; rr++)
          rmax[rr] = fmaxf(rmax[rr], __shfl_xor(rmax[rr], off, 64));
#pragma unroll
      for (int rr = 0; rr < 4; rr++) {
        const float mN = fmaxf(mrow[rf][rr], rmax[rr] * SC);
        const float al = exp2f(mrow[rf][rr] - mN);
        mrow[rf][rr] = mN;
        lsum[rf][rr] *= al;
#pragma unroll
        for (int j = 0; j < 4; j++) accO[rf][j][rr] *= al;
        rsum[rr] = 0.f;
      }
#pragma unroll
      for (int j = 0; j < 4; j++)
#pragma unroll
        for (int rr = 0; rr < 4; rr++) {
          const float p = exp2f(sa[rf][j][rr] * SC - mrow[rf][rr]);
          rsum[rr] += p;
          Ps[(w * 32 + rf * 16 + lb * 4 + rr) * KB + j * 16 + la] = f2bf(p);
        }
#pragma unroll
      for (int off = 1; off < 16; off <<= 1)
#pragma unroll
        for (int rr = 0; rr < 4; rr++) rsum[rr] += __shfl_xor(rsum[rr], off, 64);
#pragma unroll
      for (int rr = 0; rr < 4; rr++) lsum[rf][rr] += rsum[rr];
    }

#pragma unroll
    for (int ks = 0; ks < 2; ks++) {
      bf16x8 pf[2], vf[4];
#pragma unroll
      for (int rf = 0; rf < 2; rf++)
        pf[rf] = *(const bf16x8*)&Ps[(w * 32 + rf * 16 + la) * KB + ks * 32 + lb * 8];
#pragma unroll
      for (int cf = 0; cf < 4; cf++)
        vf[cf] = *(const bf16x8*)&Vt[(cf * 16 + la) * KB + ks * 32 + lb * 8];
#pragma unroll
      for (int rf = 0; rf < 2; rf++)
#pragma unroll
        for (int cf = 0; cf < 4; cf++)
          accO[rf][cf] = __builtin_amdgcn_mfma_f32_16x16x32_bf16(pf[rf], vf[cf], accO[rf][cf], 0, 0, 0);
    }
  }

#pragma unroll
  for (int rf = 0; rf < 2; rf++)
#pragma unroll
    for (int rr = 0; rr < 4; rr++) {
      const float inv = 1.0f / lsum[rf][rr];
      const int r = qrow0 + rf * 16 + lb * 4 + rr;
#pragma unroll
      for (int cf = 0; cf < 4; cf++)
        Og[base + (size_t)r * DM + cf * 16 + la] = f2bf(accO[rf][cf][rr] * inv);
    }
}

// ---------------- fused residual-add + LayerNorm (D=1024) ----------------
// AF32: A is fp32 (else bf16). OUTF32: write fp32 (else bf16).
template <int AF32, int OUTF32>
__global__ __launch_bounds__(256) void add_ln(const void* __restrict__ Ap,
                                              const u16* __restrict__ Bb,
                                              const float* __restrict__ g,
                                              const float* __restrict__ be,
                                              void* __restrict__ Yp) {
  constexpr int D = 1024;
  const int row = blockIdx.x, t = threadIdx.x;
  f32x4 a;
  if (AF32) {
    a = ((const f32x4*)((const float*)Ap + (size_t)row * D))[t];
  } else {
    u16x4 av = ((const u16x4*)((const u16*)Ap + (size_t)row * D))[t];
#pragma unroll
    for (int i = 0; i < 4; i++) a[i] = bf2f(av[i]);
  }
  u16x4 bv16 = ((const u16x4*)(Bb + (size_t)row * D))[t];
  f32x4 x;
#pragma unroll
  for (int i = 0; i < 4; i++) x[i] = a[i] + bf2f(bv16[i]);
  float s1 = x[0] + x[1] + x[2] + x[3];
  float s2 = x[0] * x[0] + x[1] * x[1] + x[2] * x[2] + x[3] * x[3];
#pragma unroll
  for (int off = 32; off > 0; off >>= 1) {
    s1 += __shfl_down(s1, off, 64);
    s2 += __shfl_down(s2, off, 64);
  }
  __shared__ float sm[8];
  const int w = t >> 6, lane = t & 63;
  if (lane == 0) { sm[w] = s1; sm[4 + w] = s2; }
  __syncthreads();
  s1 = sm[0] + sm[1] + sm[2] + sm[3];
  s2 = sm[4] + sm[5] + sm[6] + sm[7];
  const float mean = s1 * (1.0f / D);
  const float var = s2 * (1.0f / D) - mean * mean;
  const float rstd = rsqrtf(var + 1e-5f);
  const f32x4 gv = ((const f32x4*)g)[t];
  const f32x4 bv = ((const f32x4*)be)[t];
  f32x4 y;
#pragma unroll
  for (int i = 0; i < 4; i++) y[i] = (x[i] - mean) * rstd * gv[i] + bv[i];
  if (OUTF32) {
    ((f32x4*)((float*)Yp + (size_t)row * D))[t] = y;
  } else {
    u16x4 o;
#pragma unroll
    for (int i = 0; i < 4; i++) o[i] = f2bf(y[i]);
    ((u16x4*)((u16*)Yp + (size_t)row * D))[t] = o;
  }
}

extern "C" void kernel_launch(void* const* d_in, const int* in_sizes, int n_in,
                              void* d_out, int out_size, void* d_ws, size_t ws_size,
                              hipStream_t stream) {
  const float* X   = (const float*)d_in[0];
  const float* Wq  = (const float*)d_in[1];
  const float* bq  = (const float*)d_in[2];
  const float* Wk  = (const float*)d_in[3];
  const float* bk  = (const float*)d_in[4];
  const float* Wv  = (const float*)d_in[5];
  const float* bv  = (const float*)d_in[6];
  const float* Wo  = (const float*)d_in[7];
  const float* bo  = (const float*)d_in[8];
  const float* g1  = (const float*)d_in[9];
  const float* be1 = (const float*)d_in[10];
  const float* W1  = (const float*)d_in[11];
  const float* b1  = (const float*)d_in[12];
  const float* W2  = (const float*)d_in[13];
  const float* b2  = (const float*)d_in[14];
  const float* g2  = (const float*)d_in[15];
  const float* be2 = (const float*)d_in[16];

  // ---- workspace plan (peak 120 MB, lifetime-aliased) ----
  // [0,8)MB   WqT,WkT,WvT,WoT
  // [8,16)    W1T            [16,24)  W2T
  // [24,40)   Xb  -> Ab (O-proj out) -> Fb (FFN2 out)
  // [40,104)  Qb,Kb,Vb,Cx -> Hb (FFN1 out, 64MB)
  // [104,120) Yb (LN1 out, bf16)
  const size_t MB = 1ull << 20;
  char* wsb = (char*)d_ws;
  u16* WqT = (u16*)(wsb + 0 * MB);
  u16* WkT = (u16*)(wsb + 2 * MB);
  u16* WvT = (u16*)(wsb + 4 * MB);
  u16* WoT = (u16*)(wsb + 6 * MB);
  u16* W1T = (u16*)(wsb + 8 * MB);
  u16* W2T = (u16*)(wsb + 16 * MB);
  u16* Xb  = (u16*)(wsb + 24 * MB);
  u16* Ab  = (u16*)(wsb + 24 * MB);   // alias Xb (dead after V gemm)
  u16* Fb  = (u16*)(wsb + 24 * MB);   // alias Ab (dead after LN1)
  u16* Qb  = (u16*)(wsb + 40 * MB);
  u16* Kb  = (u16*)(wsb + 56 * MB);
  u16* Vb  = (u16*)(wsb + 72 * MB);
  u16* Cx  = (u16*)(wsb + 88 * MB);
  u16* Hb  = (u16*)(wsb + 40 * MB);   // alias Q/K/V/Cx (dead after O-proj)
  u16* Yb  = (u16*)(wsb + 104 * MB);
  (void)ws_size; (void)in_sizes; (void)n_in; (void)out_size;

  cast_bf16<<<2048, 256, 0, stream>>>(X, Xb, 8192 * 1024 / 8);
  transpose_cast<<<dim3(32, 32), 256, 0, stream>>>(Wq, WqT, 1024, 1024);
  transpose_cast<<<dim3(32, 32), 256, 0, stream>>>(Wk, WkT, 1024, 1024);
  transpose_cast<<<dim3(32, 32), 256, 0, stream>>>(Wv, WvT, 1024, 1024);
  transpose_cast<<<dim3(32, 32), 256, 0, stream>>>(Wo, WoT, 1024, 1024);
  transpose_cast<<<dim3(128, 32), 256, 0, stream>>>(W1, W1T, 1024, 4096);
  transpose_cast<<<dim3(32, 128), 256, 0, stream>>>(W2, W2T, 4096, 1024);

  gemm_bt<0><<<dim3(8, 64), 256, 0, stream>>>(Xb, WqT, bq, Qb, 8192, 1024, 1024);
  gemm_bt<0><<<dim3(8, 64), 256, 0, stream>>>(Xb, WkT, bk, Kb, 8192, 1024, 1024);
  gemm_bt<0><<<dim3(8, 64), 256, 0, stream>>>(Xb, WvT, bv, Vb, 8192, 1024, 1024);

  attn_fwd<<<dim3(16, 16, 4), 256, 0, stream>>>(Qb, Kb, Vb, Cx);

  gemm_bt<0><<<dim3(8, 64), 256, 0, stream>>>(Cx, WoT, bo, Ab, 8192, 1024, 1024);
  add_ln<1, 0><<<8192, 256, 0, stream>>>(X, Ab, g1, be1, Yb);
  gemm_bt<1><<<dim3(32, 64), 256, 0, stream>>>(Yb, W1T, b1, Hb, 8192, 4096, 1024);
  gemm_bt<0><<<dim3(8, 64), 256, 0, stream>>>(Hb, W2T, b2, Fb, 8192, 1024, 4096);
  add_ln<0, 1><<<8192, 256, 0, stream>>>(Yb, Fb, g2, be2, d_out);
}

// Round 3
// 630.862 us; speedup vs baseline: 1.1091x; 1.1091x over previous
//
#include <hip/hip_runtime.h>
#include <stdint.h>

typedef unsigned short u16;
typedef short bf16x8 __attribute__((ext_vector_type(8)));
typedef float f32x4 __attribute__((ext_vector_type(4)));
typedef u16 u16x4 __attribute__((ext_vector_type(4)));
typedef u16 u16x8 __attribute__((ext_vector_type(8)));

#define LOG2E 1.4426950408889634f

__device__ __forceinline__ u16 f2bf(float f) {
  union { float f; uint32_t u; } x; x.f = f;
  uint32_t r = x.u + 0x7fffu + ((x.u >> 16) & 1u);
  return (u16)(r >> 16);
}
__device__ __forceinline__ float bf2f(u16 h) {
  union { uint32_t u; float f; } x; x.u = ((uint32_t)h) << 16;
  return x.f;
}
// 16B-granule XOR swizzle: spreads both read (row varies by lane) and
// scatter-write (row&7 constant, row>>3 varies) patterns across bank slots.
__device__ __forceinline__ int swz3(int row) { return (row ^ (row >> 3)) & 7; }

__device__ __forceinline__ void gload_lds16(const void* g, void* lds) {
  __builtin_amdgcn_global_load_lds(
      (const __attribute__((address_space(1))) void*)g,
      (__attribute__((address_space(3))) void*)lds, 16, 0, 0);
}

// ---------------- cast f32 -> bf16 (8 elems/thread) ----------------
__global__ __launch_bounds__(256) void cast_bf16(const float* __restrict__ in,
                                                 u16* __restrict__ out, int n8) {
  int i = blockIdx.x * 256 + threadIdx.x;
  const int stride = gridDim.x * 256;
  for (; i < n8; i += stride) {
    const f32x4* p = (const f32x4*)in + (size_t)i * 2;
    f32x4 a = p[0], b = p[1];
    u16x8 o;
    o[0] = f2bf(a[0]); o[1] = f2bf(a[1]); o[2] = f2bf(a[2]); o[3] = f2bf(a[3]);
    o[4] = f2bf(b[0]); o[5] = f2bf(b[1]); o[6] = f2bf(b[2]); o[7] = f2bf(b[3]);
    ((u16x8*)out)[i] = o;
  }
}

// ---------------- concat 3 bias vectors (1024 each) ----------------
__global__ __launch_bounds__(256) void concat3(const float* __restrict__ a,
                                               const float* __restrict__ b,
                                               const float* __restrict__ c,
                                               float* __restrict__ o) {
  int i = blockIdx.x * 256 + threadIdx.x;
  if (i < 3072) o[i] = i < 1024 ? a[i] : (i < 2048 ? b[i - 1024] : c[i - 2048]);
}

// ---------------- transpose + cast: W[R][C] f32 -> WT[C][R] bf16 ----------------
__global__ __launch_bounds__(256) void transpose_cast(const float* __restrict__ in,
                                                      u16* __restrict__ out, int R, int C) {
  __shared__ float tile[32][33];
  const int bc = blockIdx.x * 32, br = blockIdx.y * 32;
  const int tx = threadIdx.x & 31, ty = threadIdx.x >> 5;  // 32 x 8
#pragma unroll
  for (int i = 0; i < 32; i += 8)
    tile[ty + i][tx] = in[(size_t)(br + ty + i) * C + bc + tx];
  __syncthreads();
#pragma unroll
  for (int i = 0; i < 32; i += 8)
    out[(size_t)(bc + ty + i) * R + br + tx] = f2bf(tile[tx][ty + i]);
}

// ---------------- GEMM: C[M][N] = A[M][K] @ BT[N][K]^T + bias ----------------
template <int RELU>
__global__ __launch_bounds__(256) void gemm_bt(const u16* __restrict__ A,
                                               const u16* __restrict__ BT,
                                               const float* __restrict__ bias,
                                               u16* __restrict__ Cb,
                                               int M, int N, int K) {
  constexpr int BM = 128, BN = 128, BK = 64;
  __shared__ u16 As[BM * BK];
  __shared__ u16 Bs[BN * BK];
  const int t = threadIdx.x;
  const int w = t >> 6, lane = t & 63;
  const int la = lane & 15, lb = lane >> 4;
  const int wr = w >> 1, wc = w & 1;
  const int m0 = blockIdx.y * BM, n0 = blockIdx.x * BN;

  f32x4 acc[4][4];
#pragma unroll
  for (int i = 0; i < 4; i++)
#pragma unroll
    for (int j = 0; j < 4; j++) acc[i][j] = (f32x4){0.f, 0.f, 0.f, 0.f};

  for (int kt = 0; kt < K; kt += BK) {
#pragma unroll
    for (int i = 0; i < 4; i++) {
      const int s = i * 256 + t;
      const int row = s >> 3, col = (s & 7) * 8;
      gload_lds16(A + (size_t)(m0 + row) * K + kt + col, &As[(i * 256 + w * 64) * 8]);
      gload_lds16(BT + (size_t)(n0 + row) * K + kt + col, &Bs[(i * 256 + w * 64) * 8]);
    }
    __syncthreads();
#pragma unroll
    for (int ks = 0; ks < 2; ks++) {
      bf16x8 af[4], bfr[4];
#pragma unroll
      for (int i = 0; i < 4; i++)
        af[i] = *(const bf16x8*)&As[(wr * 64 + i * 16 + la) * BK + ks * 32 + lb * 8];
#pragma unroll
      for (int j = 0; j < 4; j++)
        bfr[j] = *(const bf16x8*)&Bs[(wc * 64 + j * 16 + la) * BK + ks * 32 + lb * 8];
#pragma unroll
      for (int i = 0; i < 4; i++)
#pragma unroll
        for (int j = 0; j < 4; j++)
          acc[i][j] = __builtin_amdgcn_mfma_f32_16x16x32_bf16(af[i], bfr[j], acc[i][j], 0, 0, 0);
    }
    __syncthreads();
  }
#pragma unroll
  for (int i = 0; i < 4; i++) {
    const int r = m0 + wr * 64 + i * 16 + lb * 4;
#pragma unroll
    for (int j = 0; j < 4; j++) {
      const int c = n0 + wc * 64 + j * 16 + la;
      const float bv = bias[c];
#pragma unroll
      for (int rr = 0; rr < 4; rr++) {
        float v = acc[i][j][rr] + bv;
        if (RELU) v = fmaxf(v, 0.f);
        Cb[(size_t)(r + rr) * N + c] = f2bf(v);
      }
    }
  }
}

// ---------------- flash attention fwd (swizzled LDS) ----------------
// grid: (S/128, H, B); 4 waves, each owns 32 q-rows. KVBLK=64. D_HEAD=64.
// Q/K/V rows have stride LDM (=3072, fused QKV buffer); O has stride 1024.
__global__ __launch_bounds__(256) void attn_fwd(const u16* __restrict__ Qg,
                                                const u16* __restrict__ Kg,
                                                const u16* __restrict__ Vg,
                                                u16* __restrict__ Og, int LDM) {
  constexpr int S = 2048, DH = 64, QB = 128, KB = 64, DMO = 1024;
  __shared__ u16 Ks[KB * DH];  // [kv][dh], 16B-granule swizzled
  __shared__ u16 Vt[DH * KB];  // [dh][kv], swizzled
  __shared__ u16 Ps[QB * KB];  // [m][kv],  swizzled (per-wave 32-row slices)
  const int t = threadIdx.x, w = t >> 6, lane = t & 63;
  const int la = lane & 15, lb = lane >> 4;
  const int qb = blockIdx.x, h = blockIdx.y, b = blockIdx.z;
  const size_t base = ((size_t)b * S) * LDM + h * DH;
  const size_t obase = ((size_t)b * S) * DMO + h * DH;
  const int qrow0 = qb * QB + w * 32;

  bf16x8 qf[2][2];
#pragma unroll
  for (int rf = 0; rf < 2; rf++)
#pragma unroll
    for (int ks = 0; ks < 2; ks++)
      qf[rf][ks] = *(const bf16x8*)&Qg[base + (size_t)(qrow0 + rf * 16 + la) * LDM + ks * 32 + lb * 8];

  f32x4 accO[2][4];
  float mrow[2][4], lsum[2][4];
#pragma unroll
  for (int i = 0; i < 2; i++)
#pragma unroll
    for (int j = 0; j < 4; j++) accO[i][j] = (f32x4){0.f, 0.f, 0.f, 0.f};
#pragma unroll
  for (int i = 0; i < 2; i++)
#pragma unroll
    for (int rr = 0; rr < 4; rr++) { mrow[i][rr] = -1e30f; lsum[i][rr] = 0.f; }

  const float SC = 0.125f * LOG2E;

  for (int kt = 0; kt < S; kt += KB) {
    __syncthreads();  // prev tile's LDS reads complete
    // stage K tile, pre-swizzled global source -> linear LDS dest (rule #21)
#pragma unroll
    for (int i = 0; i < 2; i++) {
      const int s = i * 256 + t;
      const int row = s >> 3;
      const int colp = ((s & 7) ^ swz3(row)) << 3;
      gload_lds16(Kg + base + (size_t)(kt + row) * LDM + colp, &Ks[(i * 256 + w * 64) * 8]);
    }
    // stage V tile transposed into swizzled Vt[dh][kv]
#pragma unroll
    for (int i = 0; i < 2; i++) {
      const int s = i * 256 + t;
      const int row = s >> 3, col = (s & 7) * 8;
      bf16x8 vv = *(const bf16x8*)&Vg[base + (size_t)(kt + row) * LDM + col];
#pragma unroll
      for (int e = 0; e < 8; e++) {
        const int dr = col + e;
        Vt[dr * KB + (row ^ (swz3(dr) << 3))] = (u16)vv[e];
      }
    }
    __syncthreads();

    // S = Q @ K^T
    f32x4 sa[2][4];
#pragma unroll
    for (int i = 0; i < 2; i++)
#pragma unroll
      for (int j = 0; j < 4; j++) sa[i][j] = (f32x4){0.f, 0.f, 0.f, 0.f};
#pragma unroll
    for (int ks = 0; ks < 2; ks++) {
      bf16x8 kf[4];
#pragma unroll
      for (int j = 0; j < 4; j++) {
        const int r = j * 16 + la;
        kf[j] = *(const bf16x8*)&Ks[r * DH + ((((ks << 2) + lb) ^ swz3(r)) << 3)];
      }
#pragma unroll
      for (int rf = 0; rf < 2; rf++)
#pragma unroll
        for (int j = 0; j < 4; j++)
          sa[rf][j] = __builtin_amdgcn_mfma_f32_16x16x32_bf16(qf[rf][ks], kf[j], sa[rf][j], 0, 0, 0);
    }

    // online softmax (row = 4*(lane>>4)+rr; reduce over lane&15 via shfl_xor)
#pragma unroll
    for (int rf = 0; rf < 2; rf++) {
      float rmax[4], rsum[4];
#pragma unroll
      for (int rr = 0; rr < 4; rr++)
        rmax[rr] = fmaxf(fmaxf(sa[rf][0][rr], sa[rf][1][rr]), fmaxf(sa[rf][2][rr], sa[rf][3][rr]));
#pragma unroll
      for (int off = 1; off < 16; off <<= 1)
#pragma unroll
        for (int rr = 0; rr < 4; rr++)
          rmax[rr] = fmaxf(rmax[rr], __shfl_xor(rmax[rr], off, 64));
#pragma unroll
      for (int rr = 0; rr < 4; rr++) {
        const float mN = fmaxf(mrow[rf][rr], rmax[rr] * SC);
        const float al = exp2f(mrow[rf][rr] - mN);
        mrow[rf][rr] = mN;
        lsum[rf][rr] *= al;
#pragma unroll
        for (int j = 0; j < 4; j++) accO[rf][j][rr] *= al;
        rsum[rr] = 0.f;
      }
#pragma unroll
      for (int j = 0; j < 4; j++)
#pragma unroll
        for (int rr = 0; rr < 4; rr++) {
          const float p = exp2f(sa[rf][j][rr] * SC - mrow[rf][rr]);
          rsum[rr] += p;
          const int qr = w * 32 + rf * 16 + lb * 4 + rr;
          Ps[qr * KB + ((j * 16 + la) ^ (swz3(qr) << 3))] = f2bf(p);
        }
#pragma unroll
      for (int off = 1; off < 16; off <<= 1)
#pragma unroll
        for (int rr = 0; rr < 4; rr++) rsum[rr] += __shfl_xor(rsum[rr], off, 64);
#pragma unroll
      for (int rr = 0; rr < 4; rr++) lsum[rf][rr] += rsum[rr];
    }

    // O += P @ V
#pragma unroll
    for (int ks = 0; ks < 2; ks++) {
      bf16x8 pf[2], vf[4];
#pragma unroll
      for (int rf = 0; rf < 2; rf++) {
        const int qr = w * 32 + rf * 16 + la;
        pf[rf] = *(const bf16x8*)&Ps[qr * KB + ((((ks << 2) + lb) ^ swz3(qr)) << 3)];
      }
#pragma unroll
      for (int cf = 0; cf < 4; cf++) {
        const int dr = cf * 16 + la;
        vf[cf] = *(const bf16x8*)&Vt[dr * KB + ((((ks << 2) + lb) ^ swz3(dr)) << 3)];
      }
#pragma unroll
      for (int rf = 0; rf < 2; rf++)
#pragma unroll
        for (int cf = 0; cf < 4; cf++)
          accO[rf][cf] = __builtin_amdgcn_mfma_f32_16x16x32_bf16(pf[rf], vf[cf], accO[rf][cf], 0, 0, 0);
    }
  }

#pragma unroll
  for (int rf = 0; rf < 2; rf++)
#pragma unroll
    for (int rr = 0; rr < 4; rr++) {
      const float inv = 1.0f / lsum[rf][rr];
      const int r = qrow0 + rf * 16 + lb * 4 + rr;
#pragma unroll
      for (int cf = 0; cf < 4; cf++)
        Og[obase + (size_t)r * DMO + cf * 16 + la] = f2bf(accO[rf][cf][rr] * inv);
    }
}

// ---------------- fused residual-add + LayerNorm (D=1024) ----------------
template <int AF32, int OUTF32>
__global__ __launch_bounds__(256) void add_ln(const void* __restrict__ Ap,
                                              const u16* __restrict__ Bb,
                                              const float* __restrict__ g,
                                              const float* __restrict__ be,
                                              void* __restrict__ Yp) {
  constexpr int D = 1024;
  const int row = blockIdx.x, t = threadIdx.x;
  f32x4 a;
  if (AF32) {
    a = ((const f32x4*)((const float*)Ap + (size_t)row * D))[t];
  } else {
    u16x4 av = ((const u16x4*)((const u16*)Ap + (size_t)row * D))[t];
#pragma unroll
    for (int i = 0; i < 4; i++) a[i] = bf2f(av[i]);
  }
  u16x4 bv16 = ((const u16x4*)(Bb + (size_t)row * D))[t];
  f32x4 x;
#pragma unroll
  for (int i = 0; i < 4; i++) x[i] = a[i] + bf2f(bv16[i]);
  float s1 = x[0] + x[1] + x[2] + x[3];
  float s2 = x[0] * x[0] + x[1] * x[1] + x[2] * x[2] + x[3] * x[3];
#pragma unroll
  for (int off = 32; off > 0; off >>= 1) {
    s1 += __shfl_down(s1, off, 64);
    s2 += __shfl_down(s2, off, 64);
  }
  __shared__ float sm[8];
  const int w = t >> 6, lane = t & 63;
  if (lane == 0) { sm[w] = s1; sm[4 + w] = s2; }
  __syncthreads();
  s1 = sm[0] + sm[1] + sm[2] + sm[3];
  s2 = sm[4] + sm[5] + sm[6] + sm[7];
  const float mean = s1 * (1.0f / D);
  const float var = s2 * (1.0f / D) - mean * mean;
  const float rstd = rsqrtf(var + 1e-5f);
  const f32x4 gv = ((const f32x4*)g)[t];
  const f32x4 bv = ((const f32x4*)be)[t];
  f32x4 y;
#pragma unroll
  for (int i = 0; i < 4; i++) y[i] = (x[i] - mean) * rstd * gv[i] + bv[i];
  if (OUTF32) {
    ((f32x4*)((float*)Yp + (size_t)row * D))[t] = y;
  } else {
    u16x4 o;
#pragma unroll
    for (int i = 0; i < 4; i++) o[i] = f2bf(y[i]);
    ((u16x4*)((u16*)Yp + (size_t)row * D))[t] = o;
  }
}

extern "C" void kernel_launch(void* const* d_in, const int* in_sizes, int n_in,
                              void* d_out, int out_size, void* d_ws, size_t ws_size,
                              hipStream_t stream) {
  const float* X   = (const float*)d_in[0];
  const float* Wq  = (const float*)d_in[1];
  const float* bq  = (const float*)d_in[2];
  const float* Wk  = (const float*)d_in[3];
  const float* bk  = (const float*)d_in[4];
  const float* Wv  = (const float*)d_in[5];
  const float* bv  = (const float*)d_in[6];
  const float* Wo  = (const float*)d_in[7];
  const float* bo  = (const float*)d_in[8];
  const float* g1  = (const float*)d_in[9];
  const float* be1 = (const float*)d_in[10];
  const float* W1  = (const float*)d_in[11];
  const float* b1  = (const float*)d_in[12];
  const float* W2  = (const float*)d_in[13];
  const float* b2  = (const float*)d_in[14];
  const float* g2  = (const float*)d_in[15];
  const float* be2 = (const float*)d_in[16];

  // ---- workspace plan (peak 120 MB, lifetime-aliased) ----
  // [0,6)   WqkvT (3072x1024 bf16)   [6,8)  WoT
  // [8,16)  W1T                      [16,24) W2T
  // [24,40) Xb -> Ab (O-proj out) -> Fb (FFN2 out)
  // [40,88) QKVb (8192x3072 bf16) -> Hb [40,104) after O-proj
  // [88,104) bqkv (12KB, dead after QKV gemm) then Cx (attn out)
  // [104,120) Yb (LN1 out)
  const size_t MB = 1ull << 20;
  char* wsb = (char*)d_ws;
  u16*   WqkvT = (u16*)(wsb + 0 * MB);
  u16*   WoT   = (u16*)(wsb + 6 * MB);
  u16*   W1T   = (u16*)(wsb + 8 * MB);
  u16*   W2T   = (u16*)(wsb + 16 * MB);
  u16*   Xb    = (u16*)(wsb + 24 * MB);
  u16*   Ab    = (u16*)(wsb + 24 * MB);
  u16*   Fb    = (u16*)(wsb + 24 * MB);
  u16*   QKVb  = (u16*)(wsb + 40 * MB);
  u16*   Hb    = (u16*)(wsb + 40 * MB);
  float* bqkv  = (float*)(wsb + 88 * MB);
  u16*   Cx    = (u16*)(wsb + 88 * MB);
  u16*   Yb    = (u16*)(wsb + 104 * MB);
  (void)ws_size; (void)in_sizes; (void)n_in; (void)out_size;

  cast_bf16<<<2048, 256, 0, stream>>>(X, Xb, 8192 * 1024 / 8);
  concat3<<<12, 256, 0, stream>>>(bq, bk, bv, bqkv);
  transpose_cast<<<dim3(32, 32), 256, 0, stream>>>(Wq, WqkvT, 1024, 1024);
  transpose_cast<<<dim3(32, 32), 256, 0, stream>>>(Wk, WqkvT + 1024 * 1024, 1024, 1024);
  transpose_cast<<<dim3(32, 32), 256, 0, stream>>>(Wv, WqkvT + 2 * 1024 * 1024, 1024, 1024);
  transpose_cast<<<dim3(32, 32), 256, 0, stream>>>(Wo, WoT, 1024, 1024);
  transpose_cast<<<dim3(128, 32), 256, 0, stream>>>(W1, W1T, 1024, 4096);
  transpose_cast<<<dim3(32, 128), 256, 0, stream>>>(W2, W2T, 4096, 1024);

  // fused QKV projection: [8192,1024] @ [1024,3072] -> [8192,3072]
  gemm_bt<0><<<dim3(24, 64), 256, 0, stream>>>(Xb, WqkvT, bqkv, QKVb, 8192, 3072, 1024);

  attn_fwd<<<dim3(16, 16, 4), 256, 0, stream>>>(QKVb, QKVb + 1024, QKVb + 2048, Cx, 3072);

  gemm_bt<0><<<dim3(8, 64), 256, 0, stream>>>(Cx, WoT, bo, Ab, 8192, 1024, 1024);
  add_ln<1, 0><<<8192, 256, 0, stream>>>(X, Ab, g1, be1, Yb);
  gemm_bt<1><<<dim3(32, 64), 256, 0, stream>>>(Yb, W1T, b1, Hb, 8192, 4096, 1024);
  gemm_bt<0><<<dim3(8, 64), 256, 0, stream>>>(Hb, W2T, b2, Fb, 8192, 1024, 4096);
  add_ln<0, 1><<<8192, 256, 0, stream>>>(Yb, Fb, g2, be2, d_out);
}

// Round 4
// 565.956 us; speedup vs baseline: 1.2363x; 1.1147x over previous
//
#include <hip/hip_runtime.h>
#include <stdint.h>

typedef unsigned short u16;
typedef short bf16x8 __attribute__((ext_vector_type(8)));
typedef float f32x4 __attribute__((ext_vector_type(4)));
typedef u16 u16x4 __attribute__((ext_vector_type(4)));
typedef u16 u16x8 __attribute__((ext_vector_type(8)));

#define LOG2E 1.4426950408889634f

__device__ __forceinline__ u16 f2bf(float f) {
  union { float f; uint32_t u; } x; x.f = f;
  uint32_t r = x.u + 0x7fffu + ((x.u >> 16) & 1u);
  return (u16)(r >> 16);
}
// round-half-up bf16 pack (2 VALU ops); fine for finite positive values
__device__ __forceinline__ u16 f2bf_ru(float f) {
  union { float f; uint32_t u; } x; x.f = f;
  return (u16)((x.u + 0x8000u) >> 16);
}
__device__ __forceinline__ float bf2f(u16 h) {
  union { uint32_t u; float f; } x; x.u = ((uint32_t)h) << 16;
  return x.f;
}
// 16B-granule XOR swizzle: spreads both read (row varies by lane) and
// scatter-write (row&7 constant, row>>3 varies) patterns across bank slots.
__device__ __forceinline__ int swz3(int row) { return (row ^ (row >> 3)) & 7; }

__device__ __forceinline__ void gload_lds16(const void* g, void* lds) {
  __builtin_amdgcn_global_load_lds(
      (const __attribute__((address_space(1))) void*)g,
      (__attribute__((address_space(3))) void*)lds, 16, 0, 0);
}

// ---------------- cast f32 -> bf16 (8 elems/thread) ----------------
__global__ __launch_bounds__(256) void cast_bf16(const float* __restrict__ in,
                                                 u16* __restrict__ out, int n8) {
  int i = blockIdx.x * 256 + threadIdx.x;
  const int stride = gridDim.x * 256;
  for (; i < n8; i += stride) {
    const f32x4* p = (const f32x4*)in + (size_t)i * 2;
    f32x4 a = p[0], b = p[1];
    u16x8 o;
    o[0] = f2bf(a[0]); o[1] = f2bf(a[1]); o[2] = f2bf(a[2]); o[3] = f2bf(a[3]);
    o[4] = f2bf(b[0]); o[5] = f2bf(b[1]); o[6] = f2bf(b[2]); o[7] = f2bf(b[3]);
    ((u16x8*)out)[i] = o;
  }
}

// ---------------- concat 3 bias vectors (1024 each) ----------------
__global__ __launch_bounds__(256) void concat3(const float* __restrict__ a,
                                               const float* __restrict__ b,
                                               const float* __restrict__ c,
                                               float* __restrict__ o) {
  int i = blockIdx.x * 256 + threadIdx.x;
  if (i < 3072) o[i] = i < 1024 ? a[i] : (i < 2048 ? b[i - 1024] : c[i - 2048]);
}

// ---------------- transpose + cast: W[R][C] f32 -> WT[C][R] bf16 ----------------
__global__ __launch_bounds__(256) void transpose_cast(const float* __restrict__ in,
                                                      u16* __restrict__ out, int R, int C) {
  __shared__ float tile[32][33];
  const int bc = blockIdx.x * 32, br = blockIdx.y * 32;
  const int tx = threadIdx.x & 31, ty = threadIdx.x >> 5;  // 32 x 8
#pragma unroll
  for (int i = 0; i < 32; i += 8)
    tile[ty + i][tx] = in[(size_t)(br + ty + i) * C + bc + tx];
  __syncthreads();
#pragma unroll
  for (int i = 0; i < 32; i += 8)
    out[(size_t)(bc + ty + i) * R + br + tx] = f2bf(tile[tx][ty + i]);
}

// ---------------- GEMM: C[M][N] = A[M][K] @ BT[N][K]^T + bias ----------------
template <int RELU>
__global__ __launch_bounds__(256) void gemm_bt(const u16* __restrict__ A,
                                               const u16* __restrict__ BT,
                                               const float* __restrict__ bias,
                                               u16* __restrict__ Cb,
                                               int M, int N, int K) {
  constexpr int BM = 128, BN = 128, BK = 64;
  __shared__ u16 As[BM * BK];
  __shared__ u16 Bs[BN * BK];
  const int t = threadIdx.x;
  const int w = t >> 6, lane = t & 63;
  const int la = lane & 15, lb = lane >> 4;
  const int wr = w >> 1, wc = w & 1;
  const int m0 = blockIdx.y * BM, n0 = blockIdx.x * BN;

  f32x4 acc[4][4];
#pragma unroll
  for (int i = 0; i < 4; i++)
#pragma unroll
    for (int j = 0; j < 4; j++) acc[i][j] = (f32x4){0.f, 0.f, 0.f, 0.f};

  for (int kt = 0; kt < K; kt += BK) {
#pragma unroll
    for (int i = 0; i < 4; i++) {
      const int s = i * 256 + t;
      const int row = s >> 3, col = (s & 7) * 8;
      gload_lds16(A + (size_t)(m0 + row) * K + kt + col, &As[(i * 256 + w * 64) * 8]);
      gload_lds16(BT + (size_t)(n0 + row) * K + kt + col, &Bs[(i * 256 + w * 64) * 8]);
    }
    __syncthreads();
#pragma unroll
    for (int ks = 0; ks < 2; ks++) {
      bf16x8 af[4], bfr[4];
#pragma unroll
      for (int i = 0; i < 4; i++)
        af[i] = *(const bf16x8*)&As[(wr * 64 + i * 16 + la) * BK + ks * 32 + lb * 8];
#pragma unroll
      for (int j = 0; j < 4; j++)
        bfr[j] = *(const bf16x8*)&Bs[(wc * 64 + j * 16 + la) * BK + ks * 32 + lb * 8];
#pragma unroll
      for (int i = 0; i < 4; i++)
#pragma unroll
        for (int j = 0; j < 4; j++)
          acc[i][j] = __builtin_amdgcn_mfma_f32_16x16x32_bf16(af[i], bfr[j], acc[i][j], 0, 0, 0);
    }
    __syncthreads();
  }
#pragma unroll
  for (int i = 0; i < 4; i++) {
    const int r = m0 + wr * 64 + i * 16 + lb * 4;
#pragma unroll
    for (int j = 0; j < 4; j++) {
      const int c = n0 + wc * 64 + j * 16 + la;
      const float bv = bias[c];
#pragma unroll
      for (int rr = 0; rr < 4; rr++) {
        float v = acc[i][j][rr] + bv;
        if (RELU) v = fmaxf(v, 0.f);
        Cb[(size_t)(r + rr) * N + c] = f2bf(v);
      }
    }
  }
}

// ---------------- flash attention fwd (swizzled LDS, lean softmax) ----------------
// grid: (S/128, H, B); 4 waves, each owns 32 q-rows. KVBLK=64. D_HEAD=64.
__global__ __launch_bounds__(256) void attn_fwd(const u16* __restrict__ Qg,
                                                const u16* __restrict__ Kg,
                                                const u16* __restrict__ Vg,
                                                u16* __restrict__ Og, int LDM) {
  constexpr int S = 2048, DH = 64, QB = 128, KB = 64, DMO = 1024;
  __shared__ u16 Ks[KB * DH];  // [kv][dh], 16B-granule swizzled
  __shared__ u16 Vt[DH * KB];  // [dh][kv], swizzled
  __shared__ u16 Ps[QB * KB];  // [m][kv],  swizzled (per-wave 32-row slices)
  const int t = threadIdx.x, w = t >> 6, lane = t & 63;
  const int la = lane & 15, lb = lane >> 4;
  const int qb = blockIdx.x, h = blockIdx.y, b = blockIdx.z;
  const size_t base = ((size_t)b * S) * LDM + h * DH;
  const size_t obase = ((size_t)b * S) * DMO + h * DH;
  const int qrow0 = qb * QB + w * 32;

  bf16x8 qf[2][2];
#pragma unroll
  for (int rf = 0; rf < 2; rf++)
#pragma unroll
    for (int ks = 0; ks < 2; ks++)
      qf[rf][ks] = *(const bf16x8*)&Qg[base + (size_t)(qrow0 + rf * 16 + la) * LDM + ks * 32 + lb * 8];

  f32x4 accO[2][4];
  float mrow[2][4], lsum[2][4];  // lsum: PER-LANE partial, reduced at epilogue
#pragma unroll
  for (int i = 0; i < 2; i++)
#pragma unroll
    for (int j = 0; j < 4; j++) accO[i][j] = (f32x4){0.f, 0.f, 0.f, 0.f};
#pragma unroll
  for (int i = 0; i < 2; i++)
#pragma unroll
    for (int rr = 0; rr < 4; rr++) { mrow[i][rr] = -1e30f; lsum[i][rr] = 0.f; }

  const float SC = 0.125f * LOG2E;

  for (int kt = 0; kt < S; kt += KB) {
    __syncthreads();  // prev tile's LDS reads complete
    // stage K tile, pre-swizzled global source -> linear LDS dest
#pragma unroll
    for (int i = 0; i < 2; i++) {
      const int s = i * 256 + t;
      const int row = s >> 3;
      const int colp = ((s & 7) ^ swz3(row)) << 3;
      gload_lds16(Kg + base + (size_t)(kt + row) * LDM + colp, &Ks[(i * 256 + w * 64) * 8]);
    }
    // stage V tile transposed into swizzled Vt[dh][kv]
#pragma unroll
    for (int i = 0; i < 2; i++) {
      const int s = i * 256 + t;
      const int row = s >> 3, col = (s & 7) * 8;
      bf16x8 vv = *(const bf16x8*)&Vg[base + (size_t)(kt + row) * LDM + col];
#pragma unroll
      for (int e = 0; e < 8; e++) {
        const int dr = col + e;
        Vt[dr * KB + (row ^ (swz3(dr) << 3))] = (u16)vv[e];
      }
    }
    __syncthreads();

    // S = Q @ K^T
    f32x4 sa[2][4];
#pragma unroll
    for (int i = 0; i < 2; i++)
#pragma unroll
      for (int j = 0; j < 4; j++) sa[i][j] = (f32x4){0.f, 0.f, 0.f, 0.f};
#pragma unroll
    for (int ks = 0; ks < 2; ks++) {
      bf16x8 kf[4];
#pragma unroll
      for (int j = 0; j < 4; j++) {
        const int r = j * 16 + la;
        kf[j] = *(const bf16x8*)&Ks[r * DH + ((((ks << 2) + lb) ^ swz3(r)) << 3)];
      }
#pragma unroll
      for (int rf = 0; rf < 2; rf++)
#pragma unroll
        for (int j = 0; j < 4; j++)
          sa[rf][j] = __builtin_amdgcn_mfma_f32_16x16x32_bf16(qf[rf][ks], kf[j], sa[rf][j], 0, 0, 0);
    }

    // online softmax, lean: skip reduce+rescale when no lane grows the max
#pragma unroll
    for (int rf = 0; rf < 2; rf++) {
      float rmax[4];
#pragma unroll
      for (int rr = 0; rr < 4; rr++)
        rmax[rr] = fmaxf(fmaxf(sa[rf][0][rr], sa[rf][1][rr]), fmaxf(sa[rf][2][rr], sa[rf][3][rr]));
      int grow = 0;
#pragma unroll
      for (int rr = 0; rr < 4; rr++) grow |= (rmax[rr] * SC > mrow[rf][rr]);
      if (__any(grow)) {  // wave-uniform branch
#pragma unroll
        for (int off = 1; off < 16; off <<= 1)
#pragma unroll
          for (int rr = 0; rr < 4; rr++)
            rmax[rr] = fmaxf(rmax[rr], __shfl_xor(rmax[rr], off, 64));
#pragma unroll
        for (int rr = 0; rr < 4; rr++) {
          const float mN = fmaxf(mrow[rf][rr], rmax[rr] * SC);
          const float al = exp2f(mrow[rf][rr] - mN);
          mrow[rf][rr] = mN;
          lsum[rf][rr] *= al;
#pragma unroll
          for (int j = 0; j < 4; j++) accO[rf][j][rr] *= al;
        }
      }
#pragma unroll
      for (int j = 0; j < 4; j++)
#pragma unroll
        for (int rr = 0; rr < 4; rr++) {
          const float p = exp2f(sa[rf][j][rr] * SC - mrow[rf][rr]);
          lsum[rf][rr] += p;  // per-lane partial
          const int qr = w * 32 + rf * 16 + lb * 4 + rr;
          Ps[qr * KB + ((j * 16 + la) ^ (swz3(qr) << 3))] = f2bf_ru(p);
        }
    }

    // O += P @ V
#pragma unroll
    for (int ks = 0; ks < 2; ks++) {
      bf16x8 pf[2], vf[4];
#pragma unroll
      for (int rf = 0; rf < 2; rf++) {
        const int qr = w * 32 + rf * 16 + la;
        pf[rf] = *(const bf16x8*)&Ps[qr * KB + ((((ks << 2) + lb) ^ swz3(qr)) << 3)];
      }
#pragma unroll
      for (int cf = 0; cf < 4; cf++) {
        const int dr = cf * 16 + la;
        vf[cf] = *(const bf16x8*)&Vt[dr * KB + ((((ks << 2) + lb) ^ swz3(dr)) << 3)];
      }
#pragma unroll
      for (int rf = 0; rf < 2; rf++)
#pragma unroll
        for (int cf = 0; cf < 4; cf++)
          accO[rf][cf] = __builtin_amdgcn_mfma_f32_16x16x32_bf16(pf[rf], vf[cf], accO[rf][cf], 0, 0, 0);
    }
  }

  // epilogue: single cross-lane lsum reduction (over la: xor 1,2,4,8)
#pragma unroll
  for (int rf = 0; rf < 2; rf++)
#pragma unroll
    for (int off = 1; off < 16; off <<= 1)
#pragma unroll
      for (int rr = 0; rr < 4; rr++)
        lsum[rf][rr] += __shfl_xor(lsum[rf][rr], off, 64);

#pragma unroll
  for (int rf = 0; rf < 2; rf++)
#pragma unroll
    for (int rr = 0; rr < 4; rr++) {
      const float inv = 1.0f / lsum[rf][rr];
      const int r = qrow0 + rf * 16 + lb * 4 + rr;
#pragma unroll
      for (int cf = 0; cf < 4; cf++)
        Og[obase + (size_t)r * DMO + cf * 16 + la] = f2bf_ru(accO[rf][cf][rr] * inv);
    }
}

// ---------------- fused residual-add + LayerNorm (D=1024) ----------------
template <int AF32, int OUTF32>
__global__ __launch_bounds__(256) void add_ln(const void* __restrict__ Ap,
                                              const u16* __restrict__ Bb,
                                              const float* __restrict__ g,
                                              const float* __restrict__ be,
                                              void* __restrict__ Yp) {
  constexpr int D = 1024;
  const int row = blockIdx.x, t = threadIdx.x;
  f32x4 a;
  if (AF32) {
    a = ((const f32x4*)((const float*)Ap + (size_t)row * D))[t];
  } else {
    u16x4 av = ((const u16x4*)((const u16*)Ap + (size_t)row * D))[t];
#pragma unroll
    for (int i = 0; i < 4; i++) a[i] = bf2f(av[i]);
  }
  u16x4 bv16 = ((const u16x4*)(Bb + (size_t)row * D))[t];
  f32x4 x;
#pragma unroll
  for (int i = 0; i < 4; i++) x[i] = a[i] + bf2f(bv16[i]);
  float s1 = x[0] + x[1] + x[2] + x[3];
  float s2 = x[0] * x[0] + x[1] * x[1] + x[2] * x[2] + x[3] * x[3];
#pragma unroll
  for (int off = 32; off > 0; off >>= 1) {
    s1 += __shfl_down(s1, off, 64);
    s2 += __shfl_down(s2, off, 64);
  }
  __shared__ float sm[8];
  const int w = t >> 6, lane = t & 63;
  if (lane == 0) { sm[w] = s1; sm[4 + w] = s2; }
  __syncthreads();
  s1 = sm[0] + sm[1] + sm[2] + sm[3];
  s2 = sm[4] + sm[5] + sm[6] + sm[7];
  const float mean = s1 * (1.0f / D);
  const float var = s2 * (1.0f / D) - mean * mean;
  const float rstd = rsqrtf(var + 1e-5f);
  const f32x4 gv = ((const f32x4*)g)[t];
  const f32x4 bv = ((const f32x4*)be)[t];
  f32x4 y;
#pragma unroll
  for (int i = 0; i < 4; i++) y[i] = (x[i] - mean) * rstd * gv[i] + bv[i];
  if (OUTF32) {
    ((f32x4*)((float*)Yp + (size_t)row * D))[t] = y;
  } else {
    u16x4 o;
#pragma unroll
    for (int i = 0; i < 4; i++) o[i] = f2bf(y[i]);
    ((u16x4*)((u16*)Yp + (size_t)row * D))[t] = o;
  }
}

extern "C" void kernel_launch(void* const* d_in, const int* in_sizes, int n_in,
                              void* d_out, int out_size, void* d_ws, size_t ws_size,
                              hipStream_t stream) {
  const float* X   = (const float*)d_in[0];
  const float* Wq  = (const float*)d_in[1];
  const float* bq  = (const float*)d_in[2];
  const float* Wk  = (const float*)d_in[3];
  const float* bk  = (const float*)d_in[4];
  const float* Wv  = (const float*)d_in[5];
  const float* bv  = (const float*)d_in[6];
  const float* Wo  = (const float*)d_in[7];
  const float* bo  = (const float*)d_in[8];
  const float* g1  = (const float*)d_in[9];
  const float* be1 = (const float*)d_in[10];
  const float* W1  = (const float*)d_in[11];
  const float* b1  = (const float*)d_in[12];
  const float* W2  = (const float*)d_in[13];
  const float* b2  = (const float*)d_in[14];
  const float* g2  = (const float*)d_in[15];
  const float* be2 = (const float*)d_in[16];

  // ---- workspace plan (peak 120 MB, lifetime-aliased) ----
  const size_t MB = 1ull << 20;
  char* wsb = (char*)d_ws;
  u16*   WqkvT = (u16*)(wsb + 0 * MB);
  u16*   WoT   = (u16*)(wsb + 6 * MB);
  u16*   W1T   = (u16*)(wsb + 8 * MB);
  u16*   W2T   = (u16*)(wsb + 16 * MB);
  u16*   Xb    = (u16*)(wsb + 24 * MB);
  u16*   Ab    = (u16*)(wsb + 24 * MB);
  u16*   Fb    = (u16*)(wsb + 24 * MB);
  u16*   QKVb  = (u16*)(wsb + 40 * MB);
  u16*   Hb    = (u16*)(wsb + 40 * MB);
  float* bqkv  = (float*)(wsb + 88 * MB);
  u16*   Cx    = (u16*)(wsb + 88 * MB);
  u16*   Yb    = (u16*)(wsb + 104 * MB);
  (void)ws_size; (void)in_sizes; (void)n_in; (void)out_size;

  cast_bf16<<<2048, 256, 0, stream>>>(X, Xb, 8192 * 1024 / 8);
  concat3<<<12, 256, 0, stream>>>(bq, bk, bv, bqkv);
  transpose_cast<<<dim3(32, 32), 256, 0, stream>>>(Wq, WqkvT, 1024, 1024);
  transpose_cast<<<dim3(32, 32), 256, 0, stream>>>(Wk, WqkvT + 1024 * 1024, 1024, 1024);
  transpose_cast<<<dim3(32, 32), 256, 0, stream>>>(Wv, WqkvT + 2 * 1024 * 1024, 1024, 1024);
  transpose_cast<<<dim3(32, 32), 256, 0, stream>>>(Wo, WoT, 1024, 1024);
  transpose_cast<<<dim3(128, 32), 256, 0, stream>>>(W1, W1T, 1024, 4096);
  transpose_cast<<<dim3(32, 128), 256, 0, stream>>>(W2, W2T, 4096, 1024);

  // fused QKV projection: [8192,1024] @ [1024,3072] -> [8192,3072]
  gemm_bt<0><<<dim3(24, 64), 256, 0, stream>>>(Xb, WqkvT, bqkv, QKVb, 8192, 3072, 1024);

  attn_fwd<<<dim3(16, 16, 4), 256, 0, stream>>>(QKVb, QKVb + 1024, QKVb + 2048, Cx, 3072);

  gemm_bt<0><<<dim3(8, 64), 256, 0, stream>>>(Cx, WoT, bo, Ab, 8192, 1024, 1024);
  add_ln<1, 0><<<8192, 256, 0, stream>>>(X, Ab, g1, be1, Yb);
  gemm_bt<1><<<dim3(32, 64), 256, 0, stream>>>(Yb, W1T, b1, Hb, 8192, 4096, 1024);
  gemm_bt<0><<<dim3(8, 64), 256, 0, stream>>>(Hb, W2T, b2, Fb, 8192, 1024, 4096);
  add_ln<0, 1><<<8192, 256, 0, stream>>>(Yb, Fb, g2, be2, d_out);
}

// Round 5
// 533.736 us; speedup vs baseline: 1.3109x; 1.0604x over previous
//
#include <hip/hip_runtime.h>
#include <stdint.h>

typedef unsigned short u16;
typedef short bf16x8 __attribute__((ext_vector_type(8)));
typedef float f32x4 __attribute__((ext_vector_type(4)));
typedef u16 u16x4 __attribute__((ext_vector_type(4)));
typedef u16 u16x8 __attribute__((ext_vector_type(8)));

#define LOG2E 1.4426950408889634f

__device__ __forceinline__ u16 f2bf(float f) {
  union { float f; uint32_t u; } x; x.f = f;
  uint32_t r = x.u + 0x7fffu + ((x.u >> 16) & 1u);
  return (u16)(r >> 16);
}
// round-half-up bf16 pack (2 VALU ops); fine for finite values
__device__ __forceinline__ u16 f2bf_ru(float f) {
  union { float f; uint32_t u; } x; x.f = f;
  return (u16)((x.u + 0x8000u) >> 16);
}
__device__ __forceinline__ float bf2f(u16 h) {
  union { uint32_t u; float f; } x; x.u = ((uint32_t)h) << 16;
  return x.f;
}
// pack 2 f32 -> 2 bf16 in one u32 (lo in low half)
__device__ __forceinline__ uint32_t cvtpk(float lo, float hi) {
  uint32_t r;
  asm("v_cvt_pk_bf16_f32 %0, %1, %2" : "=v"(r) : "v"(lo), "v"(hi));
  return r;
}
// 16B-granule XOR swizzle
__device__ __forceinline__ int swz3(int row) { return (row ^ (row >> 3)) & 7; }

__device__ __forceinline__ void gload_lds16(const void* g, void* lds) {
  __builtin_amdgcn_global_load_lds(
      (const __attribute__((address_space(1))) void*)g,
      (__attribute__((address_space(3))) void*)lds, 16, 0, 0);
}

// ---------------- cast f32 -> bf16 (8 elems/thread) ----------------
__global__ __launch_bounds__(256) void cast_bf16(const float* __restrict__ in,
                                                 u16* __restrict__ out, int n8) {
  int i = blockIdx.x * 256 + threadIdx.x;
  const int stride = gridDim.x * 256;
  for (; i < n8; i += stride) {
    const f32x4* p = (const f32x4*)in + (size_t)i * 2;
    f32x4 a = p[0], b = p[1];
    u16x8 o;
    o[0] = f2bf(a[0]); o[1] = f2bf(a[1]); o[2] = f2bf(a[2]); o[3] = f2bf(a[3]);
    o[4] = f2bf(b[0]); o[5] = f2bf(b[1]); o[6] = f2bf(b[2]); o[7] = f2bf(b[3]);
    ((u16x8*)out)[i] = o;
  }
}

// ---------------- concat 3 bias vectors (1024 each) ----------------
__global__ __launch_bounds__(256) void concat3(const float* __restrict__ a,
                                               const float* __restrict__ b,
                                               const float* __restrict__ c,
                                               float* __restrict__ o) {
  int i = blockIdx.x * 256 + threadIdx.x;
  if (i < 3072) o[i] = i < 1024 ? a[i] : (i < 2048 ? b[i - 1024] : c[i - 2048]);
}

// ---------------- transpose + cast: W[R][C] f32 -> WT[C][R] bf16 ----------------
__global__ __launch_bounds__(256) void transpose_cast(const float* __restrict__ in,
                                                      u16* __restrict__ out, int R, int C) {
  __shared__ float tile[32][33];
  const int bc = blockIdx.x * 32, br = blockIdx.y * 32;
  const int tx = threadIdx.x & 31, ty = threadIdx.x >> 5;  // 32 x 8
#pragma unroll
  for (int i = 0; i < 32; i += 8)
    tile[ty + i][tx] = in[(size_t)(br + ty + i) * C + bc + tx];
  __syncthreads();
#pragma unroll
  for (int i = 0; i < 32; i += 8)
    out[(size_t)(bc + ty + i) * R + br + tx] = f2bf(tile[tx][ty + i]);
}

// ---------------- GEMM: C[M][N] = A[M][K] @ BT[N][K]^T + bias ----------------
template <int RELU>
__global__ __launch_bounds__(256) void gemm_bt(const u16* __restrict__ A,
                                               const u16* __restrict__ BT,
                                               const float* __restrict__ bias,
                                               u16* __restrict__ Cb,
                                               int M, int N, int K) {
  constexpr int BM = 128, BN = 128, BK = 64;
  __shared__ u16 As[BM * BK];
  __shared__ u16 Bs[BN * BK];
  const int t = threadIdx.x;
  const int w = t >> 6, lane = t & 63;
  const int la = lane & 15, lb = lane >> 4;
  const int wr = w >> 1, wc = w & 1;
  const int m0 = blockIdx.y * BM, n0 = blockIdx.x * BN;

  f32x4 acc[4][4];
#pragma unroll
  for (int i = 0; i < 4; i++)
#pragma unroll
    for (int j = 0; j < 4; j++) acc[i][j] = (f32x4){0.f, 0.f, 0.f, 0.f};

  for (int kt = 0; kt < K; kt += BK) {
#pragma unroll
    for (int i = 0; i < 4; i++) {
      const int s = i * 256 + t;
      const int row = s >> 3, col = (s & 7) * 8;
      gload_lds16(A + (size_t)(m0 + row) * K + kt + col, &As[(i * 256 + w * 64) * 8]);
      gload_lds16(BT + (size_t)(n0 + row) * K + kt + col, &Bs[(i * 256 + w * 64) * 8]);
    }
    __syncthreads();
#pragma unroll
    for (int ks = 0; ks < 2; ks++) {
      bf16x8 af[4], bfr[4];
#pragma unroll
      for (int i = 0; i < 4; i++)
        af[i] = *(const bf16x8*)&As[(wr * 64 + i * 16 + la) * BK + ks * 32 + lb * 8];
#pragma unroll
      for (int j = 0; j < 4; j++)
        bfr[j] = *(const bf16x8*)&Bs[(wc * 64 + j * 16 + la) * BK + ks * 32 + lb * 8];
#pragma unroll
      for (int i = 0; i < 4; i++)
#pragma unroll
        for (int j = 0; j < 4; j++)
          acc[i][j] = __builtin_amdgcn_mfma_f32_16x16x32_bf16(af[i], bfr[j], acc[i][j], 0, 0, 0);
    }
    __syncthreads();
  }
#pragma unroll
  for (int i = 0; i < 4; i++) {
    const int r = m0 + wr * 64 + i * 16 + lb * 4;
#pragma unroll
    for (int j = 0; j < 4; j++) {
      const int c = n0 + wc * 64 + j * 16 + la;
      const float bv = bias[c];
#pragma unroll
      for (int rr = 0; rr < 4; rr++) {
        float v = acc[i][j][rr] + bv;
        if (RELU) v = fmaxf(v, 0.f);
        Cb[(size_t)(r + rr) * N + c] = f2bf(v);
      }
    }
  }
}

// ---------------- flash attention fwd (swapped QK^T, in-register P) ----------------
// grid: (S/128, H, B); 4 waves, each owns 32 q-rows. KVBLK=64. D_HEAD=64.
// S^T = mfma(K,Q): lane holds q=la (scalar row state), kv=16j+4lb+rr.
// PV A-frag built in-register via cvt_pk + ds_bpermute exchange (no P LDS).
__global__ __launch_bounds__(256) void attn_fwd(const u16* __restrict__ Qg,
                                                const u16* __restrict__ Kg,
                                                const u16* __restrict__ Vg,
                                                u16* __restrict__ Og, int LDM) {
  constexpr int S = 2048, DH = 64, KB = 64, DMO = 1024;
  __shared__ u16 Ks[KB * DH];  // [kv][dh], 16B-granule swizzled
  __shared__ u16 Vt[DH * KB];  // [dh][kv], swizzled
  const int t = threadIdx.x, w = t >> 6, lane = t & 63;
  const int la = lane & 15, lb = lane >> 4;
  const int qb = blockIdx.x, h = blockIdx.y, b = blockIdx.z;
  const size_t base = ((size_t)b * S) * LDM + h * DH;
  const size_t obase = ((size_t)b * S) * DMO + h * DH;
  const int qrow0 = qb * 128 + w * 32;
  // bpermute sources for the kv-exchange
  const int s0 = la + 32 * (lb & 1);
  const int s1 = s0 + 16;
  const int jsel = lb >> 1;

  bf16x8 qf[2][2];
#pragma unroll
  for (int rf = 0; rf < 2; rf++)
#pragma unroll
    for (int ks = 0; ks < 2; ks++)
      qf[rf][ks] = *(const bf16x8*)&Qg[base + (size_t)(qrow0 + rf * 16 + la) * LDM + ks * 32 + lb * 8];

  f32x4 accO[2][4];
  float m[2], l[2];  // per-lane row state for q = qrow0 + 16rf + la
#pragma unroll
  for (int i = 0; i < 2; i++) {
    m[i] = -1e30f; l[i] = 0.f;
#pragma unroll
    for (int j = 0; j < 4; j++) accO[i][j] = (f32x4){0.f, 0.f, 0.f, 0.f};
  }

  const float SC = 0.125f * LOG2E;

  for (int kt = 0; kt < S; kt += KB) {
    __syncthreads();  // prev tile's LDS reads complete
    // stage K tile, pre-swizzled global source -> linear LDS dest
#pragma unroll
    for (int i = 0; i < 2; i++) {
      const int s = i * 256 + t;
      const int row = s >> 3;
      const int colp = ((s & 7) ^ swz3(row)) << 3;
      gload_lds16(Kg + base + (size_t)(kt + row) * LDM + colp, &Ks[(i * 256 + w * 64) * 8]);
    }
    // stage V tile transposed into swizzled Vt[dh][kv]
#pragma unroll
    for (int i = 0; i < 2; i++) {
      const int s = i * 256 + t;
      const int row = s >> 3, col = (s & 7) * 8;
      bf16x8 vv = *(const bf16x8*)&Vg[base + (size_t)(kt + row) * LDM + col];
#pragma unroll
      for (int e = 0; e < 8; e++) {
        const int dr = col + e;
        Vt[dr * KB + (row ^ (swz3(dr) << 3))] = (u16)vv[e];
      }
    }
    __syncthreads();

    // S^T = K @ Q^T : st[j][rf], lane holds q=la, kv=16j+4lb+rr
    f32x4 st[4][2];
#pragma unroll
    for (int j = 0; j < 4; j++)
#pragma unroll
      for (int rf = 0; rf < 2; rf++) st[j][rf] = (f32x4){0.f, 0.f, 0.f, 0.f};
    __builtin_amdgcn_s_setprio(1);
#pragma unroll
    for (int ks = 0; ks < 2; ks++) {
      bf16x8 kf[4];
#pragma unroll
      for (int j = 0; j < 4; j++) {
        const int r = j * 16 + la;
        kf[j] = *(const bf16x8*)&Ks[r * DH + ((((ks << 2) + lb) ^ swz3(r)) << 3)];
      }
#pragma unroll
      for (int j = 0; j < 4; j++)
#pragma unroll
        for (int rf = 0; rf < 2; rf++)
          st[j][rf] = __builtin_amdgcn_mfma_f32_16x16x32_bf16(kf[j], qf[rf][ks], st[j][rf], 0, 0, 0);
    }
    __builtin_amdgcn_s_setprio(0);

    bf16x8 pf[2][2];  // [rf][ks] PV A-operand, built in-register
#pragma unroll
    for (int rf = 0; rf < 2; rf++) {
      // row max over the 16 in-lane kv values, then across lb lanes
      float rm = st[0][rf][0];
#pragma unroll
      for (int j = 0; j < 4; j++)
#pragma unroll
        for (int rr = 0; rr < 4; rr++) rm = fmaxf(rm, st[j][rf][rr]);
      rm *= SC;
      if (__any(rm > m[rf])) {  // wave-uniform defer-max
        rm = fmaxf(rm, __shfl_xor(rm, 16, 64));
        rm = fmaxf(rm, __shfl_xor(rm, 32, 64));
        const float mN = fmaxf(m[rf], rm);
        const float al = exp2f(m[rf] - mN);
        m[rf] = mN;
        l[rf] *= al;
        // accO rows are q=lb*4+rr; gather al (indexed by la) per rr
#pragma unroll
        for (int rr = 0; rr < 4; rr++) {
          const float alr = __shfl(al, (lb << 2) + rr, 64);
#pragma unroll
          for (int cf = 0; cf < 4; cf++) accO[rf][cf][rr] *= alr;
        }
      }
      // p = exp2(S*SC - m), pack to bf16 pairs
      uint32_t wl[4], wh[4];
#pragma unroll
      for (int j = 0; j < 4; j++) {
        float p0 = exp2f(st[j][rf][0] * SC - m[rf]);
        float p1 = exp2f(st[j][rf][1] * SC - m[rf]);
        float p2 = exp2f(st[j][rf][2] * SC - m[rf]);
        float p3 = exp2f(st[j][rf][3] * SC - m[rf]);
        l[rf] += (p0 + p1) + (p2 + p3);
        wl[j] = cvtpk(p0, p1);
        wh[j] = cvtpk(p2, p3);
      }
      // kv-exchange: dest (la,lb) needs kv=32ks+8lb+{0..7} =
      //   words j=2ks+(lb>>1) from lanes s0 (e0..3) and s1 (e4..7)
#pragma unroll
      for (int ks = 0; ks < 2; ks++) {
        const int j0 = 2 * ks, j1 = 2 * ks + 1;
        uint32_t a0 = __shfl(wl[j0], s0, 64), a1 = __shfl(wh[j0], s0, 64);
        uint32_t a2 = __shfl(wl[j0], s1, 64), a3 = __shfl(wh[j0], s1, 64);
        uint32_t b0 = __shfl(wl[j1], s0, 64), b1 = __shfl(wh[j1], s0, 64);
        uint32_t b2 = __shfl(wl[j1], s1, 64), b3 = __shfl(wh[j1], s1, 64);
        union { uint32_t u[4]; bf16x8 v; } pk;
        pk.u[0] = jsel ? b0 : a0;
        pk.u[1] = jsel ? b1 : a1;
        pk.u[2] = jsel ? b2 : a2;
        pk.u[3] = jsel ? b3 : a3;
        pf[rf][ks] = pk.v;
      }
    }

    // O += P @ V
    __builtin_amdgcn_s_setprio(1);
#pragma unroll
    for (int ks = 0; ks < 2; ks++) {
      bf16x8 vf[4];
#pragma unroll
      for (int cf = 0; cf < 4; cf++) {
        const int dr = cf * 16 + la;
        vf[cf] = *(const bf16x8*)&Vt[dr * KB + ((((ks << 2) + lb) ^ swz3(dr)) << 3)];
      }
#pragma unroll
      for (int rf = 0; rf < 2; rf++)
#pragma unroll
        for (int cf = 0; cf < 4; cf++)
          accO[rf][cf] = __builtin_amdgcn_mfma_f32_16x16x32_bf16(pf[rf][ks], vf[cf], accO[rf][cf], 0, 0, 0);
    }
    __builtin_amdgcn_s_setprio(0);
  }

  // epilogue: reduce l across lb lanes, normalize, write
#pragma unroll
  for (int rf = 0; rf < 2; rf++) {
    float l2 = l[rf];
    l2 += __shfl_xor(l2, 16, 64);
    l2 += __shfl_xor(l2, 32, 64);
    const float inv = 1.0f / l2;
#pragma unroll
    for (int rr = 0; rr < 4; rr++) {
      const float invr = __shfl(inv, (lb << 2) + rr, 64);
      const int r = qrow0 + rf * 16 + lb * 4 + rr;
#pragma unroll
      for (int cf = 0; cf < 4; cf++)
        Og[obase + (size_t)r * DMO + cf * 16 + la] = f2bf_ru(accO[rf][cf][rr] * invr);
    }
  }
}

// ---------------- fused residual-add + LayerNorm (D=1024) ----------------
template <int AF32, int OUTF32>
__global__ __launch_bounds__(256) void add_ln(const void* __restrict__ Ap,
                                              const u16* __restrict__ Bb,
                                              const float* __restrict__ g,
                                              const float* __restrict__ be,
                                              void* __restrict__ Yp) {
  constexpr int D = 1024;
  const int row = blockIdx.x, t = threadIdx.x;
  f32x4 a;
  if (AF32) {
    a = ((const f32x4*)((const float*)Ap + (size_t)row * D))[t];
  } else {
    u16x4 av = ((const u16x4*)((const u16*)Ap + (size_t)row * D))[t];
#pragma unroll
    for (int i = 0; i < 4; i++) a[i] = bf2f(av[i]);
  }
  u16x4 bv16 = ((const u16x4*)(Bb + (size_t)row * D))[t];
  f32x4 x;
#pragma unroll
  for (int i = 0; i < 4; i++) x[i] = a[i] + bf2f(bv16[i]);
  float s1 = x[0] + x[1] + x[2] + x[3];
  float s2 = x[0] * x[0] + x[1] * x[1] + x[2] * x[2] + x[3] * x[3];
#pragma unroll
  for (int off = 32; off > 0; off >>= 1) {
    s1 += __shfl_down(s1, off, 64);
    s2 += __shfl_down(s2, off, 64);
  }
  __shared__ float sm[8];
  const int w = t >> 6, lane = t & 63;
  if (lane == 0) { sm[w] = s1; sm[4 + w] = s2; }
  __syncthreads();
  s1 = sm[0] + sm[1] + sm[2] + sm[3];
  s2 = sm[4] + sm[5] + sm[6] + sm[7];
  const float mean = s1 * (1.0f / D);
  const float var = s2 * (1.0f / D) - mean * mean;
  const float rstd = rsqrtf(var + 1e-5f);
  const f32x4 gv = ((const f32x4*)g)[t];
  const f32x4 bv = ((const f32x4*)be)[t];
  f32x4 y;
#pragma unroll
  for (int i = 0; i < 4; i++) y[i] = (x[i] - mean) * rstd * gv[i] + bv[i];
  if (OUTF32) {
    ((f32x4*)((float*)Yp + (size_t)row * D))[t] = y;
  } else {
    u16x4 o;
#pragma unroll
    for (int i = 0; i < 4; i++) o[i] = f2bf(y[i]);
    ((u16x4*)((u16*)Yp + (size_t)row * D))[t] = o;
  }
}

extern "C" void kernel_launch(void* const* d_in, const int* in_sizes, int n_in,
                              void* d_out, int out_size, void* d_ws, size_t ws_size,
                              hipStream_t stream) {
  const float* X   = (const float*)d_in[0];
  const float* Wq  = (const float*)d_in[1];
  const float* bq  = (const float*)d_in[2];
  const float* Wk  = (const float*)d_in[3];
  const float* bk  = (const float*)d_in[4];
  const float* Wv  = (const float*)d_in[5];
  const float* bv  = (const float*)d_in[6];
  const float* Wo  = (const float*)d_in[7];
  const float* bo  = (const float*)d_in[8];
  const float* g1  = (const float*)d_in[9];
  const float* be1 = (const float*)d_in[10];
  const float* W1  = (const float*)d_in[11];
  const float* b1  = (const float*)d_in[12];
  const float* W2  = (const float*)d_in[13];
  const float* b2  = (const float*)d_in[14];
  const float* g2  = (const float*)d_in[15];
  const float* be2 = (const float*)d_in[16];

  // ---- workspace plan (peak 120 MB, lifetime-aliased) ----
  const size_t MB = 1ull << 20;
  char* wsb = (char*)d_ws;
  u16*   WqkvT = (u16*)(wsb + 0 * MB);
  u16*   WoT   = (u16*)(wsb + 6 * MB);
  u16*   W1T   = (u16*)(wsb + 8 * MB);
  u16*   W2T   = (u16*)(wsb + 16 * MB);
  u16*   Xb    = (u16*)(wsb + 24 * MB);
  u16*   Ab    = (u16*)(wsb + 24 * MB);
  u16*   Fb    = (u16*)(wsb + 24 * MB);
  u16*   QKVb  = (u16*)(wsb + 40 * MB);
  u16*   Hb    = (u16*)(wsb + 40 * MB);
  float* bqkv  = (float*)(wsb + 88 * MB);
  u16*   Cx    = (u16*)(wsb + 88 * MB);
  u16*   Yb    = (u16*)(wsb + 104 * MB);
  (void)ws_size; (void)in_sizes; (void)n_in; (void)out_size;

  cast_bf16<<<2048, 256, 0, stream>>>(X, Xb, 8192 * 1024 / 8);
  concat3<<<12, 256, 0, stream>>>(bq, bk, bv, bqkv);
  transpose_cast<<<dim3(32, 32), 256, 0, stream>>>(Wq, WqkvT, 1024, 1024);
  transpose_cast<<<dim3(32, 32), 256, 0, stream>>>(Wk, WqkvT + 1024 * 1024, 1024, 1024);
  transpose_cast<<<dim3(32, 32), 256, 0, stream>>>(Wv, WqkvT + 2 * 1024 * 1024, 1024, 1024);
  transpose_cast<<<dim3(32, 32), 256, 0, stream>>>(Wo, WoT, 1024, 1024);
  transpose_cast<<<dim3(128, 32), 256, 0, stream>>>(W1, W1T, 1024, 4096);
  transpose_cast<<<dim3(32, 128), 256, 0, stream>>>(W2, W2T, 4096, 1024);

  // fused QKV projection: [8192,1024] @ [1024,3072] -> [8192,3072]
  gemm_bt<0><<<dim3(24, 64), 256, 0, stream>>>(Xb, WqkvT, bqkv, QKVb, 8192, 3072, 1024);

  attn_fwd<<<dim3(16, 16, 4), 256, 0, stream>>>(QKVb, QKVb + 1024, QKVb + 2048, Cx, 3072);

  gemm_bt<0><<<dim3(8, 64), 256, 0, stream>>>(Cx, WoT, bo, Ab, 8192, 1024, 1024);
  add_ln<1, 0><<<8192, 256, 0, stream>>>(X, Ab, g1, be1, Yb);
  gemm_bt<1><<<dim3(32, 64), 256, 0, stream>>>(Yb, W1T, b1, Hb, 8192, 4096, 1024);
  gemm_bt<0><<<dim3(8, 64), 256, 0, stream>>>(Hb, W2T, b2, Fb, 8192, 1024, 4096);
  add_ln<0, 1><<<8192, 256, 0, stream>>>(Yb, Fb, g2, be2, d_out);
}